// Round 6
// baseline (251.463 us; speedup 1.0000x reference)
//
#include <hip/hip_runtime.h>

#define AGENT __HIP_MEMORY_SCOPE_AGENT

constexpr int TD = 9, DIN = 135;
constexpr int CAP3 = 256, CAP2 = 1024, CAP1 = 4096, BK = 128;
constexpr int NB = 1024;                  // 1024 blocks x 256 thr; launch_bounds(256,4) -> 4 blocks/CU co-resident
constexpr int LSTRIDE = 32;               // 128B line spacing for sync cells
constexpr int NGRP = 32, GSZ = 32;        // arrival tree: 32 groups x 32 blocks
constexpr int NSET = 8;                   // rotating barrier sets
constexpr int NLINE = 64;                 // release lines; 16 pollers/line
constexpr int NW32 = 1600;                // bitset words for N<=51200 nodes

struct P {
  const float* x; const int* src; const int* dst; int N; int E;
  const float *W_in,*b_in,*g1W,*g1as,*g1ad,*g1b,*g2W,*g2as,*g2ad,*g2b,*g3W,*g3as,*g3ad,*g3b;
  const float *r1W,*r1b,*r2W,*r2b,*r3W,*r3b,*n1g,*n1b,*n2g,*n2b,*n3g,*n3b;
  const float *tw,*c1W,*c1b,*clg,*clb,*c2W,*c2b;
  float* tp;
  int *m3,*m2,*m1,*list3,*list2,*list1,*cnts;  // cnts[0..2]=cnt3/2/1, [8]=simsum(f32), [56]=const 0
  int *barc,*barr,*barg;
  int *bcnt1,*bcnt2,*bcnt3,*bk1,*bk2,*bk3;
  float *h0,*hh1,*es1,*ed1,*h1,*hh2,*es2,*ed2,*h2,*hh3,*es3,*ed3,*h3;
  float* dout;
};

__device__ __forceinline__ float lrelu(float v) { return v >= 0.f ? v : 0.2f * v; }

// MALL-coherent relaxed stores; readers only normal-load these lines in LATER phases.
__device__ __forceinline__ void stg(float* pp, float v) { __hip_atomic_store(pp, v, __ATOMIC_RELAXED, AGENT); }
__device__ __forceinline__ void stg(int* pp, int v)   { __hip_atomic_store(pp, v, __ATOMIC_RELAXED, AGENT); }

__device__ __forceinline__ void claim_node(int v, int* __restrict__ m, int* __restrict__ list,
                                           int* __restrict__ cnt, int cap) {
  if (atomicCAS(&m[v], -1, -2) == -1) {
    int pos = atomicAdd(cnt, 1);
    if (pos < cap) { stg(&list[pos], v); stg(&m[v], pos); } else { stg(&m[v], -3); }
  }
}

// Fence-free device-scope grid barrier (cross-phase data is MALL-coherent already).
__device__ __forceinline__ void grid_barrier(const P& p, int& lgen, int* amroot_s) {
  __syncthreads();
  int g = lgen + 1;
  if (threadIdx.x == 0) {
    *amroot_s = 0;
    int grp = blockIdx.x & (NGRP - 1);
    int* gc = &p.barc[(((g & (NSET - 1)) * NGRP) + grp) * LSTRIDE];
    if (__hip_atomic_fetch_add(gc, 1, __ATOMIC_RELAXED, AGENT) == GSZ - 1) {
      int* rc = &p.barr[(g & (NSET - 1)) * LSTRIDE];
      if (__hip_atomic_fetch_add(rc, 1, __ATOMIC_RELAXED, AGENT) == NGRP - 1) *amroot_s = 1;
    }
  }
  __syncthreads();
  if (*amroot_s) {
    if (threadIdx.x < NLINE)
      __hip_atomic_store(&p.barg[threadIdx.x * LSTRIDE], g, __ATOMIC_RELAXED, AGENT);
  } else if (threadIdx.x == 0) {
    int* line = &p.barg[(blockIdx.x & (NLINE - 1)) * LSTRIDE];
    while (__hip_atomic_load(line, __ATOMIC_RELAXED, AGENT) < g)
      __builtin_amdgcn_s_sleep(8);
  }
  __syncthreads();
  lgen = g;
}

__global__ void k_init(P p) {
  int gt = blockIdx.x * blockDim.x + threadIdx.x;
  int GT = gridDim.x * blockDim.x;
  int n3 = 3 * p.N;
  int4* mv = (int4*)p.m3;
  int4 neg = make_int4(-1, -1, -1, -1);
  int nv = n3 >> 2;
  for (int i = gt; i < nv; i += GT) mv[i] = neg;
  for (int i = (nv << 2) + gt; i < n3; i += GT) p.m3[i] = -1;
  if (gt < 64) p.cnts[gt] = 0;
  for (int i = gt; i < NSET * NGRP * LSTRIDE; i += GT) p.barc[i] = 0;
  for (int i = gt; i < NSET * LSTRIDE; i += GT) p.barr[i] = 0;
  for (int i = gt; i < NLINE * LSTRIDE; i += GT) p.barg[i] = 0;
  for (int i = gt; i < CAP2; i += GT) p.bcnt1[i] = 0;
  for (int i = gt; i < CAP3; i += GT) p.bcnt2[i] = 0;
  if (gt == 0) p.bcnt3[0] = 0;
  int total = p.N * TD;
  for (int i = gt; i < total; i += GT) {
    int v = i / TD, k = i - v * TD;
    p.tp[i] = p.x[(size_t)v * DIN + (DIN - TD) + k];
  }
}

// GAT layer for a compacted dst set (one block per dst node, 256 threads).
template <int C, int ONEXT>
__device__ void gat_phase(int nq, const int* lst, const int* mPrev,
                          const int* bket, const int* bcnt,
                          const float* hh, const float* es, const float* ed, const float* hres,
                          const float* gb, const float* rW, const float* rb,
                          const float* ng, const float* nbv, float scale,
                          float* hout, const float* Wn, const float* avn, const float* bvn,
                          float* hhn, float* esn, float* edn,
                          float* elog, int* eposs, float* sh, float* hres_s, float* shln,
                          float* psn, float* pdn, float* sc2, float* ev_s) {
  const int T = 256, Wd = 4 * C, R = Wd / T;
  int tid = threadIdx.x;
  for (int q = blockIdx.x; q < nq; q += gridDim.x) {
    int v = lst[q];
    int sp = mPrev[v];
    int nb = min(bcnt[q], BK);
    for (int j = tid; j < nb; j += T) {
      int pu = mPrev[bket[(size_t)q * BK + j]];
      eposs[j] = pu;
      const float* ep = &es[(size_t)pu * 4];
      elog[0 * BK + j] = ep[0]; elog[1 * BK + j] = ep[1];
      elog[2 * BK + j] = ep[2]; elog[3 * BK + j] = ep[3];
    }
    if (tid < 4) { ev_s[tid] = es[(size_t)sp * 4 + tid]; ev_s[4 + tid] = ed[(size_t)sp * 4 + tid]; }
    for (int k = tid; k < 128; k += T) hres_s[k] = hres[(size_t)sp * 128 + k];
    __syncthreads();
#pragma unroll
    for (int r = 0; r < R; r++) {
      int w = r * T + tid, a = w / C;
      float edv = ev_s[4 + a];
      float eself = lrelu(ev_s[a] + edv);
      float mx = eself;
      for (int j = 0; j < nb; j++) mx = fmaxf(mx, lrelu(elog[a * BK + j] + edv));
      float den = __expf(eself - mx);
      for (int j = 0; j < nb; j++) den += __expf(lrelu(elog[a * BK + j] + edv) - mx);
      float rden = 1.f / (den + 1e-16f);
      float s = __expf(eself - mx) * rden * hh[(size_t)sp * Wd + w];
      for (int j = 0; j < nb; j++)
        s += __expf(lrelu(elog[a * BK + j] + edv) - mx) * rden * hh[(size_t)eposs[j] * Wd + w];
      sh[w] = s;
    }
    __syncthreads();
    float val = 0.f;
    if (tid < C) {
      float g = 0.25f * (sh[tid] + sh[C + tid] + sh[2 * C + tid] + sh[3 * C + tid]) + gb[tid];
      g *= scale;
      g = fmaxf(g, 0.f);
      float rr = rb[tid];
      for (int k = 0; k < 128; k++) rr += hres_s[k] * rW[(size_t)k * C + tid];
      val = g + rr;
      shln[tid] = val;
    }
    __syncthreads();
    if (tid == 0) {
      float s1 = 0.f, s2 = 0.f;
      for (int k = 0; k < C; k++) { float u = shln[k]; s1 += u; s2 += u * u; }
      float mu = s1 / (float)C;
      sc2[0] = mu;
      sc2[1] = rsqrtf(fmaxf(s2 / (float)C - mu * mu, 0.f) + 1e-5f);
    }
    __syncthreads();
    if (tid < C) {
      float o = (val - sc2[0]) * sc2[1] * ng[tid] + nbv[tid];
      stg(&hout[(size_t)q * C + tid], o);
      shln[tid] = o;
    }
    __syncthreads();
    if (ONEXT > 0) {
      for (int j = tid; j < ONEXT; j += T) {
        float a2 = 0.f;
        for (int k = 0; k < C; k++) a2 += shln[k] * Wn[(size_t)k * ONEXT + j];
        stg(&hhn[(size_t)q * ONEXT + j], a2);
        psn[j] = a2 * avn[j]; pdn[j] = a2 * bvn[j];
      }
      __syncthreads();
      if (tid < 8) {
        const int CN = ONEXT / 4; int a = tid & 3;
        const float* pr = (tid < 4) ? psn : pdn;
        float s = 0.f;
        for (int c = 0; c < CN; c++) s += pr[a * CN + c];
        stg(&(tid < 4 ? esn : edn)[(size_t)q * 4 + a], s);
      }
    }
    __syncthreads();
  }
}

__global__ __launch_bounds__(256, 4) void k_mega(P p) {
  __shared__ float elog[4 * BK];
  __shared__ int   eposs[BK];
  __shared__ float sh[512];
  __shared__ float hres_s[128];
  __shared__ float shln[128];
  __shared__ float psn[512], pdn[512];
  __shared__ float sc2[2];
  __shared__ float ev_s[8];
  __shared__ float wred[4];
  __shared__ float zcl[64];
  __shared__ int   amroot_s;
  __shared__ unsigned int bs[NW32];          // membership bitset
  __shared__ float xs4[4][DIN + 1];
  __shared__ float hs4[4][128];

  int tid = threadIdx.x, bid = blockIdx.x;
  int gt = bid * 256 + tid, GT = gridDim.x * 256;
  int lgen = 0;
  float* simsum = (float*)&p.cnts[8];

  // ---- P1: cosine-sim over all E edges + claim S3 = {0} U N_in(0) ----
  {
    if (gt == 0) claim_node(0, p.m3, p.list3, &p.cnts[0], CAP3);
    float local = 0.f;
    int nq4 = p.E >> 2;
    const int4* s4p = (const int4*)p.src;
    const int4* d4p = (const int4*)p.dst;
    for (int q = gt; q < nq4; q += GT) {
      int4 s4 = s4p[q];
      int4 d4 = d4p[q];
      int ss[4] = {s4.x, s4.y, s4.z, s4.w};
      int dd[4] = {d4.x, d4.y, d4.z, d4.w};
#pragma unroll
      for (int u = 0; u < 4; u++) {
        int s = ss[u], d = dd[u];
        if (d == 0) claim_node(s, p.m3, p.list3, &p.cnts[0], CAP3);
        const float* ti = p.tp + (size_t)s * TD;
        const float* tj = p.tp + (size_t)d * TD;
        float dot = 0.f, na = 0.f, nb2 = 0.f;
#pragma unroll
        for (int k = 0; k < TD; k++) { float a = ti[k], b = tj[k]; dot += a * b; na += a * a; nb2 += b * b; }
        local += dot / (fmaxf(sqrtf(na), 1e-8f) * fmaxf(sqrtf(nb2), 1e-8f));
      }
    }
    for (int e = (nq4 << 2) + gt; e < p.E; e += GT) {
      int s = p.src[e], d = p.dst[e];
      if (d == 0) claim_node(s, p.m3, p.list3, &p.cnts[0], CAP3);
      const float* ti = p.tp + (size_t)s * TD;
      const float* tj = p.tp + (size_t)d * TD;
      float dot = 0.f, na = 0.f, nb2 = 0.f;
      for (int k = 0; k < TD; k++) { float a = ti[k], b = tj[k]; dot += a * b; na += a * a; nb2 += b * b; }
      local += dot / (fmaxf(sqrtf(na), 1e-8f) * fmaxf(sqrtf(nb2), 1e-8f));
    }
    for (int off = 32; off > 0; off >>= 1) local += __shfl_down(local, off, 64);
    if ((tid & 63) == 0) wred[tid >> 6] = local;
    __syncthreads();
    if (tid == 0) atomicAdd(simsum, wred[0] + wred[1] + wred[2] + wred[3]);
  }
  grid_barrier(p, lgen, &amroot_s);

  // ---- P2: claim S2 = S3 U N_in(S3); S3 membership via LDS bitset ----
  {
    for (int i = tid; i < NW32; i += 256) bs[i] = 0u;
    __syncthreads();
    int c3 = min(__hip_atomic_load(&p.cnts[0], __ATOMIC_RELAXED, AGENT), CAP3);
    for (int i = tid; i < c3; i += 256) {
      int v = p.list3[i];
      atomicOr(&bs[v >> 5], 1u << (v & 31));
    }
    __syncthreads();
    for (int i = gt; i < c3; i += GT) claim_node(p.list3[i], p.m2, p.list2, &p.cnts[1], CAP2);
    int nq4 = p.E >> 2;
    const int4* s4p = (const int4*)p.src;
    const int4* d4p = (const int4*)p.dst;
    for (int q = gt; q < nq4; q += GT) {
      int4 s4 = s4p[q];
      int4 d4 = d4p[q];
      int ss[4] = {s4.x, s4.y, s4.z, s4.w};
      int dd[4] = {d4.x, d4.y, d4.z, d4.w};
#pragma unroll
      for (int u = 0; u < 4; u++) {
        int d = dd[u];
        if (bs[d >> 5] & (1u << (d & 31)))
          claim_node(ss[u], p.m2, p.list2, &p.cnts[1], CAP2);
      }
    }
    for (int e = (nq4 << 2) + gt; e < p.E; e += GT) {
      int d = p.dst[e];
      if (bs[d >> 5] & (1u << (d & 31)))
        claim_node(p.src[e], p.m2, p.list2, &p.cnts[1], CAP2);
    }
  }
  grid_barrier(p, lgen, &amroot_s);

  // ---- P3: claim S1 = S2 U N_in(S2); build buckets. S2 membership via LDS bitset ----
  {
    for (int i = tid; i < NW32; i += 256) bs[i] = 0u;
    __syncthreads();
    int c2 = min(__hip_atomic_load(&p.cnts[1], __ATOMIC_RELAXED, AGENT), CAP2);
    for (int i = tid; i < c2; i += 256) {
      int v = p.list2[i];
      atomicOr(&bs[v >> 5], 1u << (v & 31));
    }
    __syncthreads();
    for (int i = gt; i < c2; i += GT) claim_node(p.list2[i], p.m1, p.list1, &p.cnts[2], CAP1);
    int nq4 = p.E >> 2;
    const int4* s4p = (const int4*)p.src;
    const int4* d4p = (const int4*)p.dst;
    for (int q = gt; q < nq4; q += GT) {
      int4 s4 = s4p[q];
      int4 d4 = d4p[q];
      int ss[4] = {s4.x, s4.y, s4.z, s4.w};
      int dd[4] = {d4.x, d4.y, d4.z, d4.w};
#pragma unroll
      for (int u = 0; u < 4; u++) {
        int s = ss[u], d = dd[u];
        if (bs[d >> 5] & (1u << (d & 31))) {
          claim_node(s, p.m1, p.list1, &p.cnts[2], CAP1);
          int p2 = p.m2[d];                        // >=0 for bitset members
          int sl = atomicAdd(&p.bcnt1[p2], 1); if (sl < BK) stg(&p.bk1[(size_t)p2 * BK + sl], s);
          int p3 = p.m3[d];                        // rare gather, only on S2 hits
          if (p3 >= 0) { int sl2 = atomicAdd(&p.bcnt2[p3], 1); if (sl2 < BK) stg(&p.bk2[(size_t)p3 * BK + sl2], s); }
          if (d == 0)  { int sl3 = atomicAdd(&p.bcnt3[0], 1);  if (sl3 < BK) stg(&p.bk3[sl3], s); }
        }
      }
    }
    for (int e = (nq4 << 2) + gt; e < p.E; e += GT) {
      int s = p.src[e], d = p.dst[e];
      if (bs[d >> 5] & (1u << (d & 31))) {
        claim_node(s, p.m1, p.list1, &p.cnts[2], CAP1);
        int p2 = p.m2[d];
        int sl = atomicAdd(&p.bcnt1[p2], 1); if (sl < BK) stg(&p.bk1[(size_t)p2 * BK + sl], s);
        int p3 = p.m3[d];
        if (p3 >= 0) { int sl2 = atomicAdd(&p.bcnt2[p3], 1); if (sl2 < BK) stg(&p.bk2[(size_t)p3 * BK + sl2], s); }
        if (d == 0)  { int sl3 = atomicAdd(&p.bcnt3[0], 1);  if (sl3 < BK) stg(&p.bk3[sl3], s); }
      }
    }
  }
  grid_barrier(p, lgen, &amroot_s);

  // ---- P4: per S1 node (batched 4/block): h0 = x@W_in+b_in ; hh1 = h0@g1W ; es1/ed1 ----
  {
    int c1 = min(__hip_atomic_load(&p.cnts[2], __ATOMIC_RELAXED, AGENT), CAP1);
    int ng4 = (c1 + 3) >> 2;
    for (int g4 = bid; g4 < ng4; g4 += gridDim.x) {
      int base = g4 * 4;
      int cnt4 = min(4, c1 - base);
      for (int u = 0; u < cnt4; u++) {
        int v = p.list1[base + u];
        for (int k = tid; k < DIN; k += 256) xs4[u][k] = p.x[(size_t)v * DIN + k];
      }
      __syncthreads();
      if (tid < 128) {
        float a0 = p.b_in[tid], a1 = a0, a2 = a0, a3 = a0;
        for (int k = 0; k < DIN; k++) {
          float w = p.W_in[(size_t)k * 128 + tid];
          a0 += xs4[0][k] * w; a1 += xs4[1][k] * w; a2 += xs4[2][k] * w; a3 += xs4[3][k] * w;
        }
        hs4[0][tid] = a0; hs4[1][tid] = a1; hs4[2][tid] = a2; hs4[3][tid] = a3;
        if (0 < cnt4) stg(&p.h0[(size_t)(base + 0) * 128 + tid], a0);
        if (1 < cnt4) stg(&p.h0[(size_t)(base + 1) * 128 + tid], a1);
        if (2 < cnt4) stg(&p.h0[(size_t)(base + 2) * 128 + tid], a2);
        if (3 < cnt4) stg(&p.h0[(size_t)(base + 3) * 128 + tid], a3);
      }
      __syncthreads();
      float b4[2][4];
#pragma unroll
      for (int jj = 0; jj < 2; jj++) {
        int j = jj * 256 + tid;
        float b0 = 0.f, b1 = 0.f, b2 = 0.f, b3 = 0.f;
        for (int k = 0; k < 128; k++) {
          float w = p.g1W[(size_t)k * 512 + j];
          b0 += hs4[0][k] * w; b1 += hs4[1][k] * w; b2 += hs4[2][k] * w; b3 += hs4[3][k] * w;
        }
        b4[jj][0] = b0; b4[jj][1] = b1; b4[jj][2] = b2; b4[jj][3] = b3;
        if (0 < cnt4) stg(&p.hh1[(size_t)(base + 0) * 512 + j], b0);
        if (1 < cnt4) stg(&p.hh1[(size_t)(base + 1) * 512 + j], b1);
        if (2 < cnt4) stg(&p.hh1[(size_t)(base + 2) * 512 + j], b2);
        if (3 < cnt4) stg(&p.hh1[(size_t)(base + 3) * 512 + j], b3);
      }
#pragma unroll
      for (int u = 0; u < 4; u++) {
        if (u >= cnt4) break;
#pragma unroll
        for (int jj = 0; jj < 2; jj++) {
          int j = jj * 256 + tid;
          psn[j] = b4[jj][u] * p.g1as[j];
          pdn[j] = b4[jj][u] * p.g1ad[j];
        }
        __syncthreads();
        if (tid < 8) {
          int a = tid & 3;
          const float* pr = (tid < 4) ? psn : pdn;
          float s = 0.f;
          for (int c = 0; c < 128; c++) s += pr[a * 128 + c];
          stg(&(tid < 4 ? p.es1 : p.ed1)[(size_t)(base + u) * 4 + a], s);
        }
        __syncthreads();
      }
    }
  }
  grid_barrier(p, lgen, &amroot_s);

  int sbits = __hip_atomic_load(&p.cnts[8], __ATOMIC_RELAXED, AGENT);
  float scale = 1.1f + 0.1f * p.tw[0] * __int_as_float(sbits) / (float)p.E;

  // ---- P5: GAT1 over S2 (+ fused proj2) ----
  {
    int c2 = min(__hip_atomic_load(&p.cnts[1], __ATOMIC_RELAXED, AGENT), CAP2);
    gat_phase<128, 512>(c2, p.list2, p.m1, p.bk1, p.bcnt1,
                        p.hh1, p.es1, p.ed1, p.h0,
                        p.g1b, p.r1W, p.r1b, p.n1g, p.n1b, scale,
                        p.h1, p.g2W, p.g2as, p.g2ad, p.hh2, p.es2, p.ed2,
                        elog, eposs, sh, hres_s, shln, psn, pdn, sc2, ev_s);
  }
  grid_barrier(p, lgen, &amroot_s);

  // ---- P6: GAT2 over S3 (+ fused proj3) ----
  {
    int c3 = min(__hip_atomic_load(&p.cnts[0], __ATOMIC_RELAXED, AGENT), CAP3);
    gat_phase<128, 256>(c3, p.list3, p.m2, p.bk2, p.bcnt2,
                        p.hh2, p.es2, p.ed2, p.h1,
                        p.g2b, p.r2W, p.r2b, p.n2g, p.n2b, scale,
                        p.h2, p.g3W, p.g3as, p.g3ad, p.hh3, p.es3, p.ed3,
                        elog, eposs, sh, hres_s, shln, psn, pdn, sc2, ev_s);
  }
  grid_barrier(p, lgen, &amroot_s);

  // ---- P7: GAT3 for node 0 only + classifier ----
  {
    gat_phase<64, 0>(1, &p.cnts[56] /* ==0 */, p.m3, p.bk3, p.bcnt3,
                     p.hh3, p.es3, p.ed3, p.h2,
                     p.g3b, p.r3W, p.r3b, p.n3g, p.n3b, 1.f,
                     p.h3, nullptr, nullptr, nullptr, nullptr, nullptr, nullptr,
                     elog, eposs, sh, hres_s, shln, psn, pdn, sc2, ev_s);
    if (bid == 0) {
      if (tid < 64) {
        float az = p.c1b[tid];
        for (int k = 0; k < 64; k++) az += shln[k] * p.c1W[k * 64 + tid];
        zcl[tid] = fmaxf(az, 0.f);
      }
      __syncthreads();
      if (tid == 0) {
        float s1 = 0.f, s2 = 0.f;
        for (int k = 0; k < 64; k++) { float u = zcl[k]; s1 += u; s2 += u * u; }
        float mu = s1 / 64.f;
        float rstd = rsqrtf(fmaxf(s2 / 64.f - mu * mu, 0.f) + 1e-5f);
        float o0 = p.c2b[0], o1 = p.c2b[1];
        for (int k = 0; k < 64; k++) {
          float zn = (zcl[k] - mu) * rstd * p.clg[k] + p.clb[k];
          o0 += zn * p.c2W[k * 2 + 0];
          o1 += zn * p.c2W[k * 2 + 1];
        }
        p.dout[0] = o0; p.dout[1] = o1;
      }
    }
  }
}

extern "C" void kernel_launch(void* const* d_in, const int* in_sizes, int n_in,
                              void* d_out, int out_size, void* d_ws, size_t ws_size,
                              hipStream_t stream) {
  P p;
  p.x = (const float*)d_in[0];
  const int* ei = (const int*)d_in[1];
  p.N = in_sizes[0] / DIN;
  p.E = in_sizes[1] / 2;
  p.src = ei; p.dst = ei + p.E;
  p.W_in = (const float*)d_in[3]; p.b_in = (const float*)d_in[4];
  p.g1W = (const float*)d_in[5]; p.g1as = (const float*)d_in[6]; p.g1ad = (const float*)d_in[7]; p.g1b = (const float*)d_in[8];
  p.g2W = (const float*)d_in[9]; p.g2as = (const float*)d_in[10]; p.g2ad = (const float*)d_in[11]; p.g2b = (const float*)d_in[12];
  p.g3W = (const float*)d_in[13]; p.g3as = (const float*)d_in[14]; p.g3ad = (const float*)d_in[15]; p.g3b = (const float*)d_in[16];
  p.r1W = (const float*)d_in[17]; p.r1b = (const float*)d_in[18];
  p.r2W = (const float*)d_in[19]; p.r2b = (const float*)d_in[20];
  p.r3W = (const float*)d_in[21]; p.r3b = (const float*)d_in[22];
  p.n1g = (const float*)d_in[23]; p.n1b = (const float*)d_in[24];
  p.n2g = (const float*)d_in[25]; p.n2b = (const float*)d_in[26];
  p.n3g = (const float*)d_in[27]; p.n3b = (const float*)d_in[28];
  p.tw  = (const float*)d_in[29];
  p.c1W = (const float*)d_in[30]; p.c1b = (const float*)d_in[31];
  p.clg = (const float*)d_in[32]; p.clb = (const float*)d_in[33];
  p.c2W = (const float*)d_in[34]; p.c2b = (const float*)d_in[35];
  p.dout = (float*)d_out;

  char* B = (char*)d_ws;
  size_t off = 0;
  auto take = [&](size_t nbytes) -> char* {
    char* r = B + off;
    off += (nbytes + 255) & ~(size_t)255;
    return r;
  };
  p.cnts  = (int*)take(256);
  p.barc  = (int*)take((size_t)NSET * NGRP * LSTRIDE * 4);
  p.barr  = (int*)take((size_t)NSET * LSTRIDE * 4);
  p.barg  = (int*)take((size_t)NLINE * LSTRIDE * 4);
  p.m3    = (int*)take((size_t)3 * p.N * 4);
  p.m2 = p.m3 + p.N; p.m1 = p.m2 + p.N;
  p.tp    = (float*)take((size_t)p.N * TD * 4);
  p.list3 = (int*)take(CAP3 * 4);
  p.list2 = (int*)take(CAP2 * 4);
  p.list1 = (int*)take(CAP1 * 4);
  p.bcnt1 = (int*)take(CAP2 * 4);
  p.bcnt2 = (int*)take(CAP3 * 4);
  p.bcnt3 = (int*)take(64);
  p.bk1   = (int*)take((size_t)CAP2 * BK * 4);
  p.bk2   = (int*)take((size_t)CAP3 * BK * 4);
  p.bk3   = (int*)take(BK * 4);
  p.h0    = (float*)take((size_t)CAP1 * 128 * 4);
  p.hh1   = (float*)take((size_t)CAP1 * 512 * 4);
  p.es1   = (float*)take((size_t)CAP1 * 16);
  p.ed1   = (float*)take((size_t)CAP1 * 16);
  p.h1    = (float*)take((size_t)CAP2 * 128 * 4);
  p.hh2   = (float*)take((size_t)CAP2 * 512 * 4);
  p.es2   = (float*)take((size_t)CAP2 * 16);
  p.ed2   = (float*)take((size_t)CAP2 * 16);
  p.h2    = (float*)take((size_t)CAP3 * 128 * 4);
  p.hh3   = (float*)take((size_t)CAP3 * 256 * 4);
  p.es3   = (float*)take((size_t)CAP3 * 16);
  p.ed3   = (float*)take((size_t)CAP3 * 16);
  p.h3    = (float*)take(64 * 4);

  k_init<<<1024, 256, 0, stream>>>(p);
  k_mega<<<NB, 256, 0, stream>>>(p);
}

// Round 7
// 201.070 us; speedup vs baseline: 1.2506x; 1.2506x over previous
//
#include <hip/hip_runtime.h>

#define AGENT __HIP_MEMORY_SCOPE_AGENT

constexpr int TD = 9, DIN = 135;
constexpr int CAP3 = 256, CAP2 = 1024, CAP1 = 4096, BK = 128;
constexpr int NB = 512;   // 512 blocks x 256 thr; launch_bounds(256,2) -> all co-resident (R5-proven)
constexpr int LSTRIDE = 32;
constexpr int NGRP = 16, GSZ = 32;        // arrival tree: 16 groups x 32 blocks
constexpr int NSET = 8;
constexpr int NLINE = 64;
constexpr int DB = 4;                     // dst nodes per block in GAT phases (weight amortization)
constexpr int PB = 8;                     // nodes per block in P4 (weight amortization)

struct P {
  const float* x; const int* src; const int* dst; int N; int E;
  const float *W_in,*b_in,*g1W,*g1as,*g1ad,*g1b,*g2W,*g2as,*g2ad,*g2b,*g3W,*g3as,*g3ad,*g3b;
  const float *r1W,*r1b,*r2W,*r2b,*r3W,*r3b,*n1g,*n1b,*n2g,*n2b,*n3g,*n3b;
  const float *tw,*c1W,*c1b,*clg,*clb,*c2W,*c2b;
  float* tp;
  int *m3,*m2,*m1,*list3,*list2,*list1,*cnts;  // cnts[0..2]=cnt3/2/1, [8]=simsum(f32), [56]=const 0
  int *barc,*barr,*barg;
  int *bcnt1,*bcnt2,*bcnt3,*bk1,*bk2,*bk3;
  float *h0,*hh1,*es1,*ed1,*h1,*hh2,*es2,*ed2,*h2,*hh3,*es3,*ed3,*h3;
  float* dout;
};

__device__ __forceinline__ float lrelu(float v) { return v >= 0.f ? v : 0.2f * v; }

// MALL-coherent relaxed stores; readers only normal-load these lines in LATER phases.
__device__ __forceinline__ void stg(float* pp, float v) { __hip_atomic_store(pp, v, __ATOMIC_RELAXED, AGENT); }
__device__ __forceinline__ void stg(int* pp, int v)   { __hip_atomic_store(pp, v, __ATOMIC_RELAXED, AGENT); }

__device__ __forceinline__ void claim_node(int v, int* __restrict__ m, int* __restrict__ list,
                                           int* __restrict__ cnt, int cap) {
  if (atomicCAS(&m[v], -1, -2) == -1) {
    int pos = atomicAdd(cnt, 1);
    if (pos < cap) { stg(&list[pos], v); stg(&m[v], pos); } else { stg(&m[v], -3); }
  }
}

// Fence-free device-scope grid barrier (cross-phase data is MALL-coherent already). [R5-proven]
__device__ __forceinline__ void grid_barrier(const P& p, int& lgen, int* amroot_s) {
  __syncthreads();
  int g = lgen + 1;
  if (threadIdx.x == 0) {
    *amroot_s = 0;
    int grp = blockIdx.x & (NGRP - 1);
    int* gc = &p.barc[(((g & (NSET - 1)) * NGRP) + grp) * LSTRIDE];
    if (__hip_atomic_fetch_add(gc, 1, __ATOMIC_RELAXED, AGENT) == GSZ - 1) {
      int* rc = &p.barr[(g & (NSET - 1)) * LSTRIDE];
      if (__hip_atomic_fetch_add(rc, 1, __ATOMIC_RELAXED, AGENT) == NGRP - 1) *amroot_s = 1;
    }
  }
  __syncthreads();
  if (*amroot_s) {
    if (threadIdx.x < NLINE)
      __hip_atomic_store(&p.barg[threadIdx.x * LSTRIDE], g, __ATOMIC_RELAXED, AGENT);
  } else if (threadIdx.x == 0) {
    int* line = &p.barg[(blockIdx.x & (NLINE - 1)) * LSTRIDE];
    while (__hip_atomic_load(line, __ATOMIC_RELAXED, AGENT) < g)
      __builtin_amdgcn_s_sleep(8);
  }
  __syncthreads();
  lgen = g;
}

__global__ void k_init(P p) {
  int gt = blockIdx.x * blockDim.x + threadIdx.x;
  int GT = gridDim.x * blockDim.x;
  int n3 = 3 * p.N;
  int4* mv = (int4*)p.m3;
  int4 neg = make_int4(-1, -1, -1, -1);
  int nv = n3 >> 2;
  for (int i = gt; i < nv; i += GT) mv[i] = neg;
  for (int i = (nv << 2) + gt; i < n3; i += GT) p.m3[i] = -1;
  if (gt < 64) p.cnts[gt] = 0;
  for (int i = gt; i < NSET * NGRP * LSTRIDE; i += GT) p.barc[i] = 0;
  for (int i = gt; i < NSET * LSTRIDE; i += GT) p.barr[i] = 0;
  for (int i = gt; i < NLINE * LSTRIDE; i += GT) p.barg[i] = 0;
  for (int i = gt; i < CAP2; i += GT) p.bcnt1[i] = 0;
  for (int i = gt; i < CAP3; i += GT) p.bcnt2[i] = 0;
  if (gt == 0) p.bcnt3[0] = 0;
  int total = p.N * TD;
  for (int i = gt; i < total; i += GT) {
    int v = i / TD, k = i - v * TD;
    p.tp[i] = p.x[(size_t)v * DIN + (DIN - TD) + k];
  }
}

// GAT layer, DB dst nodes per block-iteration. Softmax weights precomputed once per
// (dst,head); residual GEMV and next-layer projection batched over DB dsts so rW/Wn
// stream once per DB nodes instead of once per node.
template <int C, int ONEXT>
__device__ void gat_phase(int nq, const int* lst, const int* mPrev,
                          const int* bket, const int* bcnt,
                          const float* hh, const float* es, const float* ed, const float* hres,
                          const float* gb, const float* rW, const float* rb,
                          const float* ng, const float* nbv, float scale,
                          float* hout, const float* Wn, const float* avn, const float* bvn,
                          float* hhn, float* esn, float* edn,
                          float* elog4, int* eposs4, float* hres4, float* agg4, float* gm4,
                          float* selfw, int* meta, float* sc2d, float* psn, float* pdn) {
  const int Wd = 4 * C;
  int tid = threadIdx.x;
  int ngp = (nq + DB - 1) / DB;
  for (int g = blockIdx.x; g < ngp; g += gridDim.x) {
    int q0 = g * DB, nd = min(DB, nq - q0);
    if (tid < DB) {
      int sp = 0, nbu = 0;
      if (tid < nd) { int v = lst[q0 + tid]; sp = mPrev[v]; nbu = min(bcnt[q0 + tid], BK); }
      meta[tid * 2 + 0] = sp; meta[tid * 2 + 1] = nbu;
    }
    __syncthreads();
    for (int idx = tid; idx < nd * 128; idx += 256) {
      int u = idx >> 7, k = idx & 127;
      hres4[u * 128 + k] = hres[(size_t)meta[u * 2] * 128 + k];
    }
    if (tid < nd * 8) {
      int u = tid >> 3, k = tid & 7;
      selfw[u * 8 + k] = (k < 4) ? es[(size_t)meta[u * 2] * 4 + k] : ed[(size_t)meta[u * 2] * 4 + (k - 4)];
    }
    for (int u = 0; u < nd; ++u) {
      int nbu = meta[u * 2 + 1];
      for (int j = tid; j < nbu; j += 256) {
        int pu = mPrev[bket[(size_t)(q0 + u) * BK + j]];
        eposs4[u * BK + j] = pu;
        const float* ep = &es[(size_t)pu * 4];
        elog4[(u * 4 + 0) * BK + j] = ep[0]; elog4[(u * 4 + 1) * BK + j] = ep[1];
        elog4[(u * 4 + 2) * BK + j] = ep[2]; elog4[(u * 4 + 3) * BK + j] = ep[3];
      }
    }
    __syncthreads();
    // softmax weights once per (dst, head), overwrite elog4 in place
    if (tid < nd * 4) {
      int u = tid >> 2, a = tid & 3, nbu = meta[u * 2 + 1];
      float edv = selfw[u * 8 + 4 + a];
      float eself = lrelu(selfw[u * 8 + a] + edv);
      float mx = eself;
      float* el = &elog4[(u * 4 + a) * BK];
      for (int j = 0; j < nbu; j++) mx = fmaxf(mx, lrelu(el[j] + edv));
      float den = __expf(eself - mx);
      for (int j = 0; j < nbu; j++) den += __expf(lrelu(el[j] + edv) - mx);
      float rden = 1.f / (den + 1e-16f);
      for (int j = 0; j < nbu; j++) el[j] = __expf(lrelu(el[j] + edv) - mx) * rden;
      selfw[u * 8 + a] = __expf(eself - mx) * rden;
    }
    __syncthreads();
    // aggregation: pure FMA + gathers, flat over (u, w)
    for (int idx = tid; idx < nd * Wd; idx += 256) {
      int u = idx / Wd, w = idx - u * Wd, a = w / C;
      int nbu = meta[u * 2 + 1], sp = meta[u * 2];
      const float* el = &elog4[(u * 4 + a) * BK];
      const int* ej = &eposs4[u * BK];
      float s = selfw[u * 8 + a] * hh[(size_t)sp * Wd + w];
      for (int j = 0; j < nbu; j++) s += el[j] * hh[(size_t)ej[j] * Wd + w];
      agg4[u * Wd + w] = s;
    }
    __syncthreads();
    // head mean + bias + scale + relu
    for (int idx = tid; idx < nd * C; idx += 256) {
      int u = idx / C, c = idx - u * C;
      float gmv = 0.25f * (agg4[u * Wd + c] + agg4[u * Wd + C + c] +
                           agg4[u * Wd + 2 * C + c] + agg4[u * Wd + 3 * C + c]) + gb[c];
      gm4[u * C + c] = fmaxf(gmv * scale, 0.f);
    }
    __syncthreads();
    // batched residual GEMV: rW streamed once for DB dsts
    {
      const int nUg = 256 / C;
      const int K2 = (DB + nUg - 1) / nUg;
      int c = tid & (C - 1), ug = tid / C;
      float acc[K2];
#pragma unroll
      for (int t = 0; t < K2; t++) acc[t] = 0.f;
      for (int k = 0; k < 128; k++) {
        float w = rW[(size_t)k * C + c];
#pragma unroll
        for (int t = 0; t < K2; t++) { int u = ug + t * nUg; acc[t] += hres4[u * 128 + k] * w; }
      }
      float rbc = rb[c];
#pragma unroll
      for (int t = 0; t < K2; t++) {
        int u = ug + t * nUg;
        if (u < nd) gm4[u * C + c] += rbc + acc[t];
      }
    }
    __syncthreads();
    // LayerNorm: one wave per dst
    {
      int u = tid >> 6, lane = tid & 63;
      float s1 = 0.f, s2 = 0.f;
      if (u < nd) {
        for (int c = lane; c < C; c += 64) { float xv = gm4[u * C + c]; s1 += xv; s2 += xv * xv; }
      }
      for (int off = 32; off > 0; off >>= 1) { s1 += __shfl_down(s1, off, 64); s2 += __shfl_down(s2, off, 64); }
      if (lane == 0 && u < nd) {
        float mu = s1 / (float)C;
        sc2d[u * 2 + 0] = mu;
        sc2d[u * 2 + 1] = rsqrtf(fmaxf(s2 / (float)C - mu * mu, 0.f) + 1e-5f);
      }
    }
    __syncthreads();
    for (int idx = tid; idx < nd * C; idx += 256) {
      int u = idx / C, c = idx - u * C;
      float o = (gm4[u * C + c] - sc2d[u * 2]) * sc2d[u * 2 + 1] * ng[c] + nbv[c];
      stg(&hout[(size_t)(q0 + u) * C + c], o);
      gm4[u * C + c] = o;
    }
    __syncthreads();
    // batched next-layer projection: Wn streamed once for DB dsts
    if (ONEXT > 0) {
      const int JJ = (ONEXT > 0) ? (ONEXT / 256) : 1;
      float accp[JJ][DB];
#pragma unroll
      for (int jj = 0; jj < JJ; jj++) {
        int j = jj * 256 + tid;
        float a0 = 0.f, a1 = 0.f, a2 = 0.f, a3 = 0.f;
        for (int k = 0; k < C; k++) {
          float w = Wn[(size_t)k * ONEXT + j];
          a0 += gm4[0 * C + k] * w; a1 += gm4[1 * C + k] * w;
          a2 += gm4[2 * C + k] * w; a3 += gm4[3 * C + k] * w;
        }
        accp[jj][0] = a0; accp[jj][1] = a1; accp[jj][2] = a2; accp[jj][3] = a3;
        if (0 < nd) stg(&hhn[(size_t)(q0 + 0) * ONEXT + j], a0);
        if (1 < nd) stg(&hhn[(size_t)(q0 + 1) * ONEXT + j], a1);
        if (2 < nd) stg(&hhn[(size_t)(q0 + 2) * ONEXT + j], a2);
        if (3 < nd) stg(&hhn[(size_t)(q0 + 3) * ONEXT + j], a3);
      }
      for (int u = 0; u < nd; u++) {
#pragma unroll
        for (int jj = 0; jj < JJ; jj++) {
          int j = jj * 256 + tid;
          psn[j] = accp[jj][u] * avn[j];
          pdn[j] = accp[jj][u] * bvn[j];
        }
        __syncthreads();
        if (tid < 8) {
          const int CN = ONEXT / 4; int a = tid & 3;
          const float* pr = (tid < 4) ? psn : pdn;
          float s = 0.f;
          for (int cc = 0; cc < CN; cc++) s += pr[a * CN + cc];
          stg(&(tid < 4 ? esn : edn)[(size_t)(q0 + u) * 4 + a], s);
        }
        __syncthreads();
      }
    }
    __syncthreads();
  }
}

__global__ __launch_bounds__(256, 2) void k_mega(P p) {
  __shared__ float elog4[DB * 4 * BK];   // 8KB
  __shared__ int   eposs4[DB * BK];      // 2KB
  __shared__ float hres4[DB * 128];      // 2KB
  __shared__ float agg4[DB * 512];       // 8KB
  __shared__ float gm4[DB * 128];        // 2KB
  __shared__ float selfw[DB * 8];
  __shared__ int   meta[DB * 2];
  __shared__ float sc2d[DB * 2];
  __shared__ float psn[512], pdn[512];   // 4KB
  __shared__ float xs8[PB * DIN];        // 4.3KB
  __shared__ float hs8[PB * 128];        // 4KB
  __shared__ int   vid8[PB];
  __shared__ float wred[4];
  __shared__ float zcl[64];
  __shared__ int   amroot_s;

  int tid = threadIdx.x, bid = blockIdx.x;
  int gt = bid * 256 + tid, GT = gridDim.x * 256;
  int lgen = 0;
  float* simsum = (float*)&p.cnts[8];

  // ---- P1: cosine-sim over all E edges + claim S3 = {0} U N_in(0) ----
  {
    if (gt == 0) claim_node(0, p.m3, p.list3, &p.cnts[0], CAP3);
    float local = 0.f;
    for (int e = gt; e < p.E; e += GT) {
      int s = p.src[e], d = p.dst[e];
      if (d == 0) claim_node(s, p.m3, p.list3, &p.cnts[0], CAP3);
      const float* ti = p.tp + (size_t)s * TD;
      const float* tj = p.tp + (size_t)d * TD;
      float dot = 0.f, na = 0.f, nb2 = 0.f;
#pragma unroll
      for (int k = 0; k < TD; k++) { float a = ti[k], b = tj[k]; dot += a * b; na += a * a; nb2 += b * b; }
      local += dot / (fmaxf(sqrtf(na), 1e-8f) * fmaxf(sqrtf(nb2), 1e-8f));
    }
    for (int off = 32; off > 0; off >>= 1) local += __shfl_down(local, off, 64);
    if ((tid & 63) == 0) wred[tid >> 6] = local;
    __syncthreads();
    if (tid == 0) atomicAdd(simsum, wred[0] + wred[1] + wred[2] + wred[3]);
  }
  grid_barrier(p, lgen, &amroot_s);

  // ---- P2: claim S2 = S3 U N_in(S3) ----
  {
    int c3 = min(__hip_atomic_load(&p.cnts[0], __ATOMIC_RELAXED, AGENT), CAP3);
    for (int i = gt; i < c3; i += GT) claim_node(p.list3[i], p.m2, p.list2, &p.cnts[1], CAP2);
    for (int e = gt; e < p.E; e += GT)
      if (p.m3[p.dst[e]] >= 0) claim_node(p.src[e], p.m2, p.list2, &p.cnts[1], CAP2);
  }
  grid_barrier(p, lgen, &amroot_s);

  // ---- P3: claim S1 = S2 U N_in(S2), build per-dst edge buckets (raw src ids) ----
  {
    int c2 = min(__hip_atomic_load(&p.cnts[1], __ATOMIC_RELAXED, AGENT), CAP2);
    for (int i = gt; i < c2; i += GT) claim_node(p.list2[i], p.m1, p.list1, &p.cnts[2], CAP1);
    for (int e = gt; e < p.E; e += GT) {
      int s = p.src[e], d = p.dst[e];
      int p2 = p.m2[d];
      if (p2 >= 0) {
        claim_node(s, p.m1, p.list1, &p.cnts[2], CAP1);
        int sl = atomicAdd(&p.bcnt1[p2], 1); if (sl < BK) stg(&p.bk1[(size_t)p2 * BK + sl], s);
      }
      int p3 = p.m3[d];
      if (p3 >= 0) { int sl2 = atomicAdd(&p.bcnt2[p3], 1); if (sl2 < BK) stg(&p.bk2[(size_t)p3 * BK + sl2], s); }
      if (d == 0)  { int sl3 = atomicAdd(&p.bcnt3[0], 1);  if (sl3 < BK) stg(&p.bk3[sl3], s); }
    }
  }
  grid_barrier(p, lgen, &amroot_s);

  // ---- P4: batched PB nodes/block: h0 = x@W_in+b_in ; hh1 = h0@g1W ; es1/ed1 ----
  {
    int c1 = min(__hip_atomic_load(&p.cnts[2], __ATOMIC_RELAXED, AGENT), CAP1);
    int ngp = (c1 + PB - 1) / PB;
    for (int g = bid; g < ngp; g += gridDim.x) {
      int base = g * PB, nn = min(PB, c1 - base);
      if (tid < nn) vid8[tid] = p.list1[base + tid];
      __syncthreads();
      for (int idx = tid; idx < nn * DIN; idx += 256) {
        int u = idx / DIN, k = idx - u * DIN;
        xs8[u * DIN + k] = p.x[(size_t)vid8[u] * DIN + k];
      }
      __syncthreads();
      if (tid < 128) {
        float a[PB]; float bi = p.b_in[tid];
#pragma unroll
        for (int u = 0; u < PB; u++) a[u] = bi;
        for (int k = 0; k < DIN; k++) {
          float w = p.W_in[(size_t)k * 128 + tid];
#pragma unroll
          for (int u = 0; u < PB; u++) a[u] += xs8[u * DIN + k] * w;
        }
#pragma unroll
        for (int u = 0; u < PB; u++) {
          hs8[u * 128 + tid] = a[u];
          if (u < nn) stg(&p.h0[(size_t)(base + u) * 128 + tid], a[u]);
        }
      }
      __syncthreads();
      float bsv[2][PB];
#pragma unroll
      for (int jj = 0; jj < 2; jj++) {
        int j = jj * 256 + tid;
        float b[PB];
#pragma unroll
        for (int u = 0; u < PB; u++) b[u] = 0.f;
        for (int k = 0; k < 128; k++) {
          float w = p.g1W[(size_t)k * 512 + j];
#pragma unroll
          for (int u = 0; u < PB; u++) b[u] += hs8[u * 128 + k] * w;
        }
#pragma unroll
        for (int u = 0; u < PB; u++) {
          bsv[jj][u] = b[u];
          if (u < nn) stg(&p.hh1[(size_t)(base + u) * 512 + j], b[u]);
        }
      }
      for (int u = 0; u < nn; u++) {
#pragma unroll
        for (int jj = 0; jj < 2; jj++) {
          int j = jj * 256 + tid;
          psn[j] = bsv[jj][u] * p.g1as[j];
          pdn[j] = bsv[jj][u] * p.g1ad[j];
        }
        __syncthreads();
        if (tid < 8) {
          int a = tid & 3;
          const float* pr = (tid < 4) ? psn : pdn;
          float s = 0.f;
          for (int cc = 0; cc < 128; cc++) s += pr[a * 128 + cc];
          stg(&(tid < 4 ? p.es1 : p.ed1)[(size_t)(base + u) * 4 + a], s);
        }
        __syncthreads();
      }
    }
  }
  grid_barrier(p, lgen, &amroot_s);

  int sbits = __hip_atomic_load(&p.cnts[8], __ATOMIC_RELAXED, AGENT);
  float scale = 1.1f + 0.1f * p.tw[0] * __int_as_float(sbits) / (float)p.E;

  // ---- P5: GAT1 over S2 (+ fused proj2) ----
  {
    int c2 = min(__hip_atomic_load(&p.cnts[1], __ATOMIC_RELAXED, AGENT), CAP2);
    gat_phase<128, 512>(c2, p.list2, p.m1, p.bk1, p.bcnt1,
                        p.hh1, p.es1, p.ed1, p.h0,
                        p.g1b, p.r1W, p.r1b, p.n1g, p.n1b, scale,
                        p.h1, p.g2W, p.g2as, p.g2ad, p.hh2, p.es2, p.ed2,
                        elog4, eposs4, hres4, agg4, gm4, selfw, meta, sc2d, psn, pdn);
  }
  grid_barrier(p, lgen, &amroot_s);

  // ---- P6: GAT2 over S3 (+ fused proj3) ----
  {
    int c3 = min(__hip_atomic_load(&p.cnts[0], __ATOMIC_RELAXED, AGENT), CAP3);
    gat_phase<128, 256>(c3, p.list3, p.m2, p.bk2, p.bcnt2,
                        p.hh2, p.es2, p.ed2, p.h1,
                        p.g2b, p.r2W, p.r2b, p.n2g, p.n2b, scale,
                        p.h2, p.g3W, p.g3as, p.g3ad, p.hh3, p.es3, p.ed3,
                        elog4, eposs4, hres4, agg4, gm4, selfw, meta, sc2d, psn, pdn);
  }
  grid_barrier(p, lgen, &amroot_s);

  // ---- P7: GAT3 for node 0 only + classifier (block 0) ----
  {
    gat_phase<64, 0>(1, &p.cnts[56] /* ==0 */, p.m3, p.bk3, p.bcnt3,
                     p.hh3, p.es3, p.ed3, p.h2,
                     p.g3b, p.r3W, p.r3b, p.n3g, p.n3b, 1.f,
                     p.h3, nullptr, nullptr, nullptr, nullptr, nullptr, nullptr,
                     elog4, eposs4, hres4, agg4, gm4, selfw, meta, sc2d, psn, pdn);
    if (bid == 0) {
      if (tid < 64) {
        float az = p.c1b[tid];
        for (int k = 0; k < 64; k++) az += gm4[k] * p.c1W[k * 64 + tid];
        zcl[tid] = fmaxf(az, 0.f);
      }
      __syncthreads();
      if (tid == 0) {
        float s1 = 0.f, s2 = 0.f;
        for (int k = 0; k < 64; k++) { float u = zcl[k]; s1 += u; s2 += u * u; }
        float mu = s1 / 64.f;
        float rstd = rsqrtf(fmaxf(s2 / 64.f - mu * mu, 0.f) + 1e-5f);
        float o0 = p.c2b[0], o1 = p.c2b[1];
        for (int k = 0; k < 64; k++) {
          float zn = (zcl[k] - mu) * rstd * p.clg[k] + p.clb[k];
          o0 += zn * p.c2W[k * 2 + 0];
          o1 += zn * p.c2W[k * 2 + 1];
        }
        p.dout[0] = o0; p.dout[1] = o1;
      }
    }
  }
}

extern "C" void kernel_launch(void* const* d_in, const int* in_sizes, int n_in,
                              void* d_out, int out_size, void* d_ws, size_t ws_size,
                              hipStream_t stream) {
  P p;
  p.x = (const float*)d_in[0];
  const int* ei = (const int*)d_in[1];
  p.N = in_sizes[0] / DIN;
  p.E = in_sizes[1] / 2;
  p.src = ei; p.dst = ei + p.E;
  p.W_in = (const float*)d_in[3]; p.b_in = (const float*)d_in[4];
  p.g1W = (const float*)d_in[5]; p.g1as = (const float*)d_in[6]; p.g1ad = (const float*)d_in[7]; p.g1b = (const float*)d_in[8];
  p.g2W = (const float*)d_in[9]; p.g2as = (const float*)d_in[10]; p.g2ad = (const float*)d_in[11]; p.g2b = (const float*)d_in[12];
  p.g3W = (const float*)d_in[13]; p.g3as = (const float*)d_in[14]; p.g3ad = (const float*)d_in[15]; p.g3b = (const float*)d_in[16];
  p.r1W = (const float*)d_in[17]; p.r1b = (const float*)d_in[18];
  p.r2W = (const float*)d_in[19]; p.r2b = (const float*)d_in[20];
  p.r3W = (const float*)d_in[21]; p.r3b = (const float*)d_in[22];
  p.n1g = (const float*)d_in[23]; p.n1b = (const float*)d_in[24];
  p.n2g = (const float*)d_in[25]; p.n2b = (const float*)d_in[26];
  p.n3g = (const float*)d_in[27]; p.n3b = (const float*)d_in[28];
  p.tw  = (const float*)d_in[29];
  p.c1W = (const float*)d_in[30]; p.c1b = (const float*)d_in[31];
  p.clg = (const float*)d_in[32]; p.clb = (const float*)d_in[33];
  p.c2W = (const float*)d_in[34]; p.c2b = (const float*)d_in[35];
  p.dout = (float*)d_out;

  char* B = (char*)d_ws;
  size_t off = 0;
  auto take = [&](size_t nbytes) -> char* {
    char* r = B + off;
    off += (nbytes + 255) & ~(size_t)255;
    return r;
  };
  p.cnts  = (int*)take(256);
  p.barc  = (int*)take((size_t)NSET * NGRP * LSTRIDE * 4);
  p.barr  = (int*)take((size_t)NSET * LSTRIDE * 4);
  p.barg  = (int*)take((size_t)NLINE * LSTRIDE * 4);
  p.m3    = (int*)take((size_t)3 * p.N * 4);
  p.m2 = p.m3 + p.N; p.m1 = p.m2 + p.N;
  p.tp    = (float*)take((size_t)p.N * TD * 4);
  p.list3 = (int*)take(CAP3 * 4);
  p.list2 = (int*)take(CAP2 * 4);
  p.list1 = (int*)take(CAP1 * 4);
  p.bcnt1 = (int*)take(CAP2 * 4);
  p.bcnt2 = (int*)take(CAP3 * 4);
  p.bcnt3 = (int*)take(64);
  p.bk1   = (int*)take((size_t)CAP2 * BK * 4);
  p.bk2   = (int*)take((size_t)CAP3 * BK * 4);
  p.bk3   = (int*)take(BK * 4);
  p.h0    = (float*)take((size_t)CAP1 * 128 * 4);
  p.hh1   = (float*)take((size_t)CAP1 * 512 * 4);
  p.es1   = (float*)take((size_t)CAP1 * 16);
  p.ed1   = (float*)take((size_t)CAP1 * 16);
  p.h1    = (float*)take((size_t)CAP2 * 128 * 4);
  p.hh2   = (float*)take((size_t)CAP2 * 512 * 4);
  p.es2   = (float*)take((size_t)CAP2 * 16);
  p.ed2   = (float*)take((size_t)CAP2 * 16);
  p.h2    = (float*)take((size_t)CAP3 * 128 * 4);
  p.hh3   = (float*)take((size_t)CAP3 * 256 * 4);
  p.es3   = (float*)take((size_t)CAP3 * 16);
  p.ed3   = (float*)take((size_t)CAP3 * 16);
  p.h3    = (float*)take(64 * 4);

  k_init<<<1024, 256, 0, stream>>>(p);
  k_mega<<<NB, 256, 0, stream>>>(p);
}

// Round 8
// 136.403 us; speedup vs baseline: 1.8435x; 1.4741x over previous
//
#include <hip/hip_runtime.h>

constexpr int TD = 9, TDP = 12, DIN = 135;
constexpr int CAP3 = 256, CAP2 = 1024, CAP1 = 4096, BK = 128;
constexpr int PB = 4;     // nodes per block in k_h0

struct P {
  const float* x; const int* src; const int* dst; int N; int E;
  const float *W_in,*b_in,*g1W,*g1as,*g1ad,*g1b,*g2W,*g2as,*g2ad,*g2b,*g3W,*g3as,*g3ad,*g3b;
  const float *r1W,*r1b,*r2W,*r2b,*r3W,*r3b,*n1g,*n1b,*n2g,*n2b,*n3g,*n3b;
  const float *tw,*c1W,*c1b,*clg,*clb,*c2W,*c2b;
  float* tp;
  int *m3,*m2,*m1,*list3,*list2,*list1,*cnts;  // cnts[0..2]=cnt3/2/1, [8]=simsum(f32), [56]=const 0
  int *bcnt1,*bcnt2,*bcnt3,*bk1,*bk2,*bk3;
  float *h0,*hh1,*es1,*ed1,*h1,*hh2,*es2,*ed2,*h2,*hh3,*es3,*ed3,*h3;
  float* dout;
};

__device__ __forceinline__ float lrelu(float v) { return v >= 0.f ? v : 0.2f * v; }

// CAS-claim node v into (m, list, cnt). m[v] starts -1. Plain stores OK: list/m[v]
// are only read by LATER dispatches (kernel boundary flushes/invalidates L2).
__device__ __forceinline__ void claim_node(int v, int* __restrict__ m, int* __restrict__ list,
                                           int* __restrict__ cnt, int cap) {
  if (atomicCAS(&m[v], -1, -2) == -1) {
    int pos = atomicAdd(cnt, 1);
    if (pos < cap) { list[pos] = v; m[v] = pos; } else { m[v] = -3; }
  }
}

// init: maps=-1, counters=0, bucket counts=0, pack tp = x[:,126:135] padded to 12 floats
__global__ void k_init(P p) {
  int gt = blockIdx.x * blockDim.x + threadIdx.x;
  int GT = gridDim.x * blockDim.x;
  int n3 = 3 * p.N;
  int4* mv = (int4*)p.m3;
  int4 neg = make_int4(-1, -1, -1, -1);
  int nv = n3 >> 2;
  for (int i = gt; i < nv; i += GT) mv[i] = neg;
  for (int i = (nv << 2) + gt; i < n3; i += GT) p.m3[i] = -1;
  if (gt < 64) p.cnts[gt] = 0;
  for (int i = gt; i < CAP2; i += GT) p.bcnt1[i] = 0;
  for (int i = gt; i < CAP3; i += GT) p.bcnt2[i] = 0;
  if (gt == 0) p.bcnt3[0] = 0;
  int total = p.N * TDP;
  for (int i = gt; i < total; i += GT) {
    int v = i / TDP, k = i - v * TDP;
    p.tp[i] = (k < TD) ? p.x[(size_t)v * DIN + (DIN - TD) + k] : 0.f;
  }
}

// P1: cosine-sim over all E edges + claim S3 = {0} U N_in(0)
__global__ void k_sim(P p) {
  __shared__ float wred[4];
  int tid = threadIdx.x;
  int gt = blockIdx.x * blockDim.x + tid, GT = gridDim.x * blockDim.x;
  if (gt == 0) claim_node(0, p.m3, p.list3, &p.cnts[0], CAP3);
  const float4* t4 = (const float4*)p.tp;
  float local = 0.f;
  auto edge_sim = [&](int s, int d) {
    if (d == 0) claim_node(s, p.m3, p.list3, &p.cnts[0], CAP3);
    float4 a0 = t4[s * 3], a1 = t4[s * 3 + 1], a2 = t4[s * 3 + 2];
    float4 b0 = t4[d * 3], b1 = t4[d * 3 + 1], b2 = t4[d * 3 + 2];
    float dot = a0.x*b0.x + a0.y*b0.y + a0.z*b0.z + a0.w*b0.w
              + a1.x*b1.x + a1.y*b1.y + a1.z*b1.z + a1.w*b1.w
              + a2.x*b2.x + a2.y*b2.y + a2.z*b2.z + a2.w*b2.w;
    float na = a0.x*a0.x + a0.y*a0.y + a0.z*a0.z + a0.w*a0.w
             + a1.x*a1.x + a1.y*a1.y + a1.z*a1.z + a1.w*a1.w
             + a2.x*a2.x + a2.y*a2.y + a2.z*a2.z + a2.w*a2.w;
    float nb = b0.x*b0.x + b0.y*b0.y + b0.z*b0.z + b0.w*b0.w
             + b1.x*b1.x + b1.y*b1.y + b1.z*b1.z + b1.w*b1.w
             + b2.x*b2.x + b2.y*b2.y + b2.z*b2.z + b2.w*b2.w;
    local += dot / (fmaxf(sqrtf(na), 1e-8f) * fmaxf(sqrtf(nb), 1e-8f));
  };
  int nq4 = p.E >> 2;
  const int4* s4p = (const int4*)p.src;
  const int4* d4p = (const int4*)p.dst;
  for (int q = gt; q < nq4; q += GT) {
    int4 s4 = s4p[q], d4 = d4p[q];
    edge_sim(s4.x, d4.x); edge_sim(s4.y, d4.y); edge_sim(s4.z, d4.z); edge_sim(s4.w, d4.w);
  }
  for (int e = (nq4 << 2) + gt; e < p.E; e += GT) edge_sim(p.src[e], p.dst[e]);
  for (int off = 32; off > 0; off >>= 1) local += __shfl_down(local, off, 64);
  if ((tid & 63) == 0) wred[tid >> 6] = local;
  __syncthreads();
  if (tid == 0) atomicAdd((float*)&p.cnts[8], wred[0] + wred[1] + wred[2] + wred[3]);
}

// P2: claim S2 = S3 U N_in(S3)
__global__ void k_s2(P p) {
  int gt = blockIdx.x * blockDim.x + threadIdx.x, GT = gridDim.x * blockDim.x;
  int c3 = min(p.cnts[0], CAP3);
  for (int i = gt; i < c3; i += GT) claim_node(p.list3[i], p.m2, p.list2, &p.cnts[1], CAP2);
  int nq4 = p.E >> 2;
  const int4* s4p = (const int4*)p.src;
  const int4* d4p = (const int4*)p.dst;
  for (int q = gt; q < nq4; q += GT) {
    int4 s4 = s4p[q], d4 = d4p[q];
    if (p.m3[d4.x] >= 0) claim_node(s4.x, p.m2, p.list2, &p.cnts[1], CAP2);
    if (p.m3[d4.y] >= 0) claim_node(s4.y, p.m2, p.list2, &p.cnts[1], CAP2);
    if (p.m3[d4.z] >= 0) claim_node(s4.z, p.m2, p.list2, &p.cnts[1], CAP2);
    if (p.m3[d4.w] >= 0) claim_node(s4.w, p.m2, p.list2, &p.cnts[1], CAP2);
  }
  for (int e = (nq4 << 2) + gt; e < p.E; e += GT)
    if (p.m3[p.dst[e]] >= 0) claim_node(p.src[e], p.m2, p.list2, &p.cnts[1], CAP2);
}

// P3: claim S1 = S2 U N_in(S2); build per-dst edge buckets (raw src ids)
__global__ void k_s1(P p) {
  int gt = blockIdx.x * blockDim.x + threadIdx.x, GT = gridDim.x * blockDim.x;
  int c2 = min(p.cnts[1], CAP2);
  for (int i = gt; i < c2; i += GT) claim_node(p.list2[i], p.m1, p.list1, &p.cnts[2], CAP1);
  auto do_edge = [&](int s, int d) {
    int p2 = p.m2[d];
    if (p2 >= 0) {
      claim_node(s, p.m1, p.list1, &p.cnts[2], CAP1);
      int sl = atomicAdd(&p.bcnt1[p2], 1); if (sl < BK) p.bk1[(size_t)p2 * BK + sl] = s;
      int p3 = p.m3[d];
      if (p3 >= 0) { int sl2 = atomicAdd(&p.bcnt2[p3], 1); if (sl2 < BK) p.bk2[(size_t)p3 * BK + sl2] = s; }
      if (d == 0)  { int sl3 = atomicAdd(&p.bcnt3[0], 1);  if (sl3 < BK) p.bk3[sl3] = s; }
    }
  };
  int nq4 = p.E >> 2;
  const int4* s4p = (const int4*)p.src;
  const int4* d4p = (const int4*)p.dst;
  for (int q = gt; q < nq4; q += GT) {
    int4 s4 = s4p[q], d4 = d4p[q];
    do_edge(s4.x, d4.x); do_edge(s4.y, d4.y); do_edge(s4.z, d4.z); do_edge(s4.w, d4.w);
  }
  for (int e = (nq4 << 2) + gt; e < p.E; e += GT) do_edge(p.src[e], p.dst[e]);
}

// P4: batched PB nodes/block: h0 = x@W_in+b_in ; hh1 = h0@g1W ; es1/ed1 head sums
__global__ __launch_bounds__(256) void k_h0(P p) {
  __shared__ float xs[PB][DIN];
  __shared__ float hs[PB][128];
  __shared__ float psn[512], pdn[512];
  __shared__ int vid[PB];
  int tid = threadIdx.x;
  int c1 = min(p.cnts[2], CAP1);
  int ngp = (c1 + PB - 1) / PB;
  for (int g = blockIdx.x; g < ngp; g += gridDim.x) {
    int base = g * PB, nn = min(PB, c1 - base);
    if (tid < nn) vid[tid] = p.list1[base + tid];
    __syncthreads();
    for (int idx = tid; idx < nn * DIN; idx += 256) {
      int u = idx / DIN, k = idx - u * DIN;
      xs[u][k] = p.x[(size_t)vid[u] * DIN + k];
    }
    __syncthreads();
    if (tid < 128) {
      float a[PB]; float bi = p.b_in[tid];
#pragma unroll
      for (int u = 0; u < PB; u++) a[u] = bi;
      for (int k = 0; k < DIN; k++) {
        float w = p.W_in[(size_t)k * 128 + tid];
#pragma unroll
        for (int u = 0; u < PB; u++) a[u] += xs[u][k] * w;
      }
#pragma unroll
      for (int u = 0; u < PB; u++) {
        hs[u][tid] = a[u];
        if (u < nn) p.h0[(size_t)(base + u) * 128 + tid] = a[u];
      }
    }
    __syncthreads();
    float bsv[2][PB];
#pragma unroll
    for (int jj = 0; jj < 2; jj++) {
      int j = jj * 256 + tid;
      float b[PB];
#pragma unroll
      for (int u = 0; u < PB; u++) b[u] = 0.f;
      for (int k = 0; k < 128; k++) {
        float w = p.g1W[(size_t)k * 512 + j];
#pragma unroll
        for (int u = 0; u < PB; u++) b[u] += hs[u][k] * w;
      }
#pragma unroll
      for (int u = 0; u < PB; u++) {
        bsv[jj][u] = b[u];
        if (u < nn) p.hh1[(size_t)(base + u) * 512 + j] = b[u];
      }
    }
    for (int u = 0; u < nn; u++) {
#pragma unroll
      for (int jj = 0; jj < 2; jj++) {
        int j = jj * 256 + tid;
        psn[j] = bsv[jj][u] * p.g1as[j];
        pdn[j] = bsv[jj][u] * p.g1ad[j];
      }
      __syncthreads();
      if (tid < 8) {
        int a = tid & 3;
        const float* pr = (tid < 4) ? psn : pdn;
        float s = 0.f;
        for (int cc = 0; cc < 128; cc++) s += pr[a * 128 + cc];
        (tid < 4 ? p.es1 : p.ed1)[(size_t)(base + u) * 4 + a] = s;
      }
      __syncthreads();
    }
  }
}

// GAT layer kernel (one dst/block-iteration, 256 threads). Fused next-layer projection
// (ONEXT>0) or final classifier (CLS).
template <int C, int ONEXT, bool SCALE, bool CLS>
__global__ __launch_bounds__(256) void k_gat(
    const int* __restrict__ lst, const int* __restrict__ cntDp, int capD,
    const int* __restrict__ mPrev,
    const int* __restrict__ bket, const int* __restrict__ bcnt,
    const float* __restrict__ hh, const float* __restrict__ es, const float* __restrict__ ed,
    const float* __restrict__ hres,
    const float* __restrict__ gb, const float* __restrict__ rW, const float* __restrict__ rb,
    const float* __restrict__ ng, const float* __restrict__ nbv,
    const float* __restrict__ simsum, const float* __restrict__ twp, int E,
    float* __restrict__ hout,
    const float* __restrict__ Wn, const float* __restrict__ avn, const float* __restrict__ bvn,
    float* __restrict__ hhn, float* __restrict__ esn, float* __restrict__ edn,
    const float* __restrict__ c1W, const float* __restrict__ c1b,
    const float* __restrict__ clg, const float* __restrict__ clb,
    const float* __restrict__ c2W, const float* __restrict__ c2b, float* __restrict__ dout) {
  const int Wd = 4 * C, R = Wd / 256;
  constexpr int PSZ = (ONEXT > 0) ? ONEXT : 1;
  __shared__ float elog[4 * BK];
  __shared__ int   eposs[BK];
  __shared__ float ev_s[8];
  __shared__ float sh[512];
  __shared__ float hres_s[128];
  __shared__ float shln[128];
  __shared__ float psn[PSZ], pdn[PSZ];
  __shared__ float sc2[2];
  __shared__ float zcl[64];
  int tid = threadIdx.x;
  int nq = CLS ? 1 : min(*cntDp, capD);
  float scale = 1.f;
  if (SCALE) scale = 1.1f + 0.1f * twp[0] * simsum[0] / (float)E;
  for (int q = blockIdx.x; q < nq; q += gridDim.x) {
    int v = lst[q];
    int sp = mPrev[v];
    int nb = min(bcnt[q], BK);
    for (int j = tid; j < nb; j += 256) {
      int pu = mPrev[bket[(size_t)q * BK + j]];
      eposs[j] = pu;
      const float* ep = &es[(size_t)pu * 4];
      elog[0 * BK + j] = ep[0]; elog[1 * BK + j] = ep[1];
      elog[2 * BK + j] = ep[2]; elog[3 * BK + j] = ep[3];
    }
    if (tid < 4) { ev_s[tid] = es[(size_t)sp * 4 + tid]; ev_s[4 + tid] = ed[(size_t)sp * 4 + tid]; }
    for (int k = tid; k < 128; k += 256) hres_s[k] = hres[(size_t)sp * 128 + k];
    __syncthreads();
#pragma unroll
    for (int r = 0; r < R; r++) {
      int w = r * 256 + tid, a = w / C;
      float edv = ev_s[4 + a];
      float eself = lrelu(ev_s[a] + edv);
      float mx = eself;
      for (int j = 0; j < nb; j++) mx = fmaxf(mx, lrelu(elog[a * BK + j] + edv));
      float den = __expf(eself - mx);
      for (int j = 0; j < nb; j++) den += __expf(lrelu(elog[a * BK + j] + edv) - mx);
      float rden = 1.f / (den + 1e-16f);
      float s = __expf(eself - mx) * rden * hh[(size_t)sp * Wd + w];
      for (int j = 0; j < nb; j++)
        s += __expf(lrelu(elog[a * BK + j] + edv) - mx) * rden * hh[(size_t)eposs[j] * Wd + w];
      sh[w] = s;
    }
    __syncthreads();
    float val = 0.f;
    if (tid < C) {
      float g = 0.25f * (sh[tid] + sh[C + tid] + sh[2 * C + tid] + sh[3 * C + tid]) + gb[tid];
      g *= scale;
      g = fmaxf(g, 0.f);
      float rr = rb[tid];
      for (int k = 0; k < 128; k++) rr += hres_s[k] * rW[(size_t)k * C + tid];
      val = g + rr;
      shln[tid] = val;
    }
    __syncthreads();
    if (tid == 0) {
      float s1 = 0.f, s2 = 0.f;
      for (int k = 0; k < C; k++) { float u = shln[k]; s1 += u; s2 += u * u; }
      float mu = s1 / (float)C;
      sc2[0] = mu;
      sc2[1] = rsqrtf(fmaxf(s2 / (float)C - mu * mu, 0.f) + 1e-5f);
    }
    __syncthreads();
    if (tid < C) {
      float o = (val - sc2[0]) * sc2[1] * ng[tid] + nbv[tid];
      hout[(size_t)q * C + tid] = o;
      shln[tid] = o;
    }
    __syncthreads();
    if (ONEXT > 0) {
      for (int j = tid; j < ONEXT; j += 256) {
        float a2 = 0.f;
        for (int k = 0; k < C; k++) a2 += shln[k] * Wn[(size_t)k * ONEXT + j];
        hhn[(size_t)q * ONEXT + j] = a2;
        psn[j] = a2 * avn[j]; pdn[j] = a2 * bvn[j];
      }
      __syncthreads();
      if (tid < 8) {
        const int CN = ONEXT / 4; int a = tid & 3;
        const float* pr = (tid < 4) ? psn : pdn;
        float s = 0.f;
        for (int cc = 0; cc < CN; cc++) s += pr[a * CN + cc];
        (tid < 4 ? esn : edn)[(size_t)q * 4 + a] = s;
      }
      __syncthreads();
    }
    if (CLS) {
      if (tid < 64) {
        float az = c1b[tid];
        for (int k = 0; k < 64; k++) az += shln[k] * c1W[k * 64 + tid];
        zcl[tid] = fmaxf(az, 0.f);
      }
      __syncthreads();
      if (tid == 0) {
        float s1 = 0.f, s2 = 0.f;
        for (int k = 0; k < 64; k++) { float u = zcl[k]; s1 += u; s2 += u * u; }
        float mu = s1 / 64.f;
        float rstd = rsqrtf(fmaxf(s2 / 64.f - mu * mu, 0.f) + 1e-5f);
        float o0 = c2b[0], o1 = c2b[1];
        for (int k = 0; k < 64; k++) {
          float zn = (zcl[k] - mu) * rstd * clg[k] + clb[k];
          o0 += zn * c2W[k * 2 + 0];
          o1 += zn * c2W[k * 2 + 1];
        }
        dout[0] = o0; dout[1] = o1;
      }
      __syncthreads();
    }
  }
}

extern "C" void kernel_launch(void* const* d_in, const int* in_sizes, int n_in,
                              void* d_out, int out_size, void* d_ws, size_t ws_size,
                              hipStream_t stream) {
  P p;
  p.x = (const float*)d_in[0];
  const int* ei = (const int*)d_in[1];
  p.N = in_sizes[0] / DIN;
  p.E = in_sizes[1] / 2;
  p.src = ei; p.dst = ei + p.E;
  p.W_in = (const float*)d_in[3]; p.b_in = (const float*)d_in[4];
  p.g1W = (const float*)d_in[5]; p.g1as = (const float*)d_in[6]; p.g1ad = (const float*)d_in[7]; p.g1b = (const float*)d_in[8];
  p.g2W = (const float*)d_in[9]; p.g2as = (const float*)d_in[10]; p.g2ad = (const float*)d_in[11]; p.g2b = (const float*)d_in[12];
  p.g3W = (const float*)d_in[13]; p.g3as = (const float*)d_in[14]; p.g3ad = (const float*)d_in[15]; p.g3b = (const float*)d_in[16];
  p.r1W = (const float*)d_in[17]; p.r1b = (const float*)d_in[18];
  p.r2W = (const float*)d_in[19]; p.r2b = (const float*)d_in[20];
  p.r3W = (const float*)d_in[21]; p.r3b = (const float*)d_in[22];
  p.n1g = (const float*)d_in[23]; p.n1b = (const float*)d_in[24];
  p.n2g = (const float*)d_in[25]; p.n2b = (const float*)d_in[26];
  p.n3g = (const float*)d_in[27]; p.n3b = (const float*)d_in[28];
  p.tw  = (const float*)d_in[29];
  p.c1W = (const float*)d_in[30]; p.c1b = (const float*)d_in[31];
  p.clg = (const float*)d_in[32]; p.clb = (const float*)d_in[33];
  p.c2W = (const float*)d_in[34]; p.c2b = (const float*)d_in[35];
  p.dout = (float*)d_out;

  char* B = (char*)d_ws;
  size_t off = 0;
  auto take = [&](size_t nbytes) -> char* {
    char* r = B + off;
    off += (nbytes + 255) & ~(size_t)255;
    return r;
  };
  p.cnts  = (int*)take(256);
  p.m3    = (int*)take((size_t)3 * p.N * 4);
  p.m2 = p.m3 + p.N; p.m1 = p.m2 + p.N;
  p.tp    = (float*)take((size_t)p.N * TDP * 4);
  p.list3 = (int*)take(CAP3 * 4);
  p.list2 = (int*)take(CAP2 * 4);
  p.list1 = (int*)take(CAP1 * 4);
  p.bcnt1 = (int*)take(CAP2 * 4);
  p.bcnt2 = (int*)take(CAP3 * 4);
  p.bcnt3 = (int*)take(64);
  p.bk1   = (int*)take((size_t)CAP2 * BK * 4);
  p.bk2   = (int*)take((size_t)CAP3 * BK * 4);
  p.bk3   = (int*)take(BK * 4);
  p.h0    = (float*)take((size_t)CAP1 * 128 * 4);
  p.hh1   = (float*)take((size_t)CAP1 * 512 * 4);
  p.es1   = (float*)take((size_t)CAP1 * 16);
  p.ed1   = (float*)take((size_t)CAP1 * 16);
  p.h1    = (float*)take((size_t)CAP2 * 128 * 4);
  p.hh2   = (float*)take((size_t)CAP2 * 512 * 4);
  p.es2   = (float*)take((size_t)CAP2 * 16);
  p.ed2   = (float*)take((size_t)CAP2 * 16);
  p.h2    = (float*)take((size_t)CAP3 * 128 * 4);
  p.hh3   = (float*)take((size_t)CAP3 * 256 * 4);
  p.es3   = (float*)take((size_t)CAP3 * 16);
  p.ed3   = (float*)take((size_t)CAP3 * 16);
  p.h3    = (float*)take(64 * 4);

  k_init<<<1024, 256, 0, stream>>>(p);
  k_sim<<<1024, 256, 0, stream>>>(p);
  k_s2<<<1024, 256, 0, stream>>>(p);
  k_s1<<<1024, 256, 0, stream>>>(p);
  k_h0<<<512, 256, 0, stream>>>(p);
  k_gat<128, 512, true, false><<<256, 256, 0, stream>>>(
      p.list2, &p.cnts[1], CAP2, p.m1, p.bk1, p.bcnt1,
      p.hh1, p.es1, p.ed1, p.h0, p.g1b, p.r1W, p.r1b, p.n1g, p.n1b,
      (const float*)&p.cnts[8], p.tw, p.E, p.h1,
      p.g2W, p.g2as, p.g2ad, p.hh2, p.es2, p.ed2,
      nullptr, nullptr, nullptr, nullptr, nullptr, nullptr, nullptr);
  k_gat<128, 256, true, false><<<64, 256, 0, stream>>>(
      p.list3, &p.cnts[0], CAP3, p.m2, p.bk2, p.bcnt2,
      p.hh2, p.es2, p.ed2, p.h1, p.g2b, p.r2W, p.r2b, p.n2g, p.n2b,
      (const float*)&p.cnts[8], p.tw, p.E, p.h2,
      p.g3W, p.g3as, p.g3ad, p.hh3, p.es3, p.ed3,
      nullptr, nullptr, nullptr, nullptr, nullptr, nullptr, nullptr);
  k_gat<64, 0, false, true><<<1, 256, 0, stream>>>(
      &p.cnts[56] /* ==0 */, &p.cnts[0], CAP3, p.m3, p.bk3, p.bcnt3,
      p.hh3, p.es3, p.ed3, p.h2, p.g3b, p.r3W, p.r3b, p.n3g, p.n3b,
      (const float*)&p.cnts[8], p.tw, p.E, p.h3,
      nullptr, nullptr, nullptr, nullptr, nullptr, nullptr,
      p.c1W, p.c1b, p.clg, p.clb, p.c2W, p.c2b, p.dout);
}